// Round 4
// baseline (405.940 us; speedup 1.0000x reference)
//
#include <hip/hip_runtime.h>

#define F 64
#define H 64
#define HPAD 72          // bf16 elems per LDS row: 144 B (16B-aligned; Bh reads conflict-free, writes ~2-way)
#define NT 256
#define TILE_ROWS 128
#define ITERS 8
#define ROWS_PER_BLOCK (TILE_ROWS * ITERS)   // 1024

typedef __bf16 bf16;
typedef __attribute__((ext_vector_type(8))) __bf16 bf16x8;
typedef __attribute__((ext_vector_type(4))) __bf16 bf16x4;
typedef __attribute__((ext_vector_type(4))) float f32x4;

__device__ __forceinline__ float celu1(float v) {
    // CELU(alpha=1): x>0 ? x : exp(x)-1
    float e = __expf(v) - 1.0f;
    return v > 0.0f ? v : e;
}

// one-shot fp32 -> bf16 convert of w_hid into d_ws (re-run every launch: ws is re-poisoned)
__global__ __launch_bounds__(256) void conv_w(const float* __restrict__ w, bf16* __restrict__ wc) {
    int i = (blockIdx.x * 256 + threadIdx.x) * 4;
    float4 v = *(const float4*)(w + i);
    bf16x4 o; o[0] = (bf16)v.x; o[1] = (bf16)v.y; o[2] = (bf16)v.z; o[3] = (bf16)v.w;
    *(bf16x4*)(wc + i) = o;
}

// Block = one feature f x 1024 rows. 4 waves, each owns 32 rows per 128-row tile, 8 tiles.
// All three layers are MFMA on the transposed product C^T[out][batch]:
//   A[m=out][k=in] (W rows, register-resident), B[k=in][n=batch] (hbuf rows / x regs),
//   D: col=batch=lane&15, row=out=16*m16+quad*4+reg.
// Layer 1 (in=1) is a compensated rank-1: k0=w_hi*x_hi, k1=w_lo*x_hi, k2=w_hi*x_lo.
// Layer 2 output is dotted with w_out in registers (quad shfl reduce) -> no LDS round trip.
//
// blockIdx swizzle: bid = s*128 + (r*4 + g), f = g*16+s, rowgroup = r. All 16 blocks
// sharing an x/out 64B line (same r,g; s=0..15) get the same bid%8 -> same XCD ->
// line fetched once, partial writes merge in that XCD's L2 (fixes R3's 507MB FETCH).
template<bool WBF16>
__global__ __launch_bounds__(NT, 4) void mlp64(
    const float* __restrict__ x,
    const float* __restrict__ w_in,
    const float* __restrict__ b_in,
    const float* __restrict__ w_hid,
    const float* __restrict__ b_hid,
    const float* __restrict__ w_out,
    const float* __restrict__ b_out,
    const bf16*  __restrict__ wc,
    float* __restrict__ out)
{
    const int bid  = blockIdx.x;
    const int s    = bid >> 7;            // f & 15
    const int low  = bid & 127;           // r*4 + g
    const int r    = low >> 2;            // row-group
    const int g    = low & 3;             // f >> 4
    const int f    = g * 16 + s;
    const int row0 = r * ROWS_PER_BLOCK;

    const int t    = threadIdx.x;
    const int lane = t & 63;
    const int wave = t >> 6;
    const int l15  = lane & 15;
    const int quad = lane >> 4;
    const int wrow = wave * 32;

    __shared__ __align__(16) bf16 hbuf[TILE_ROWS][HPAD];  // wave-private 32-row slices
    __shared__ float s_bias[3][H];                        // [0]=b_in, [1]=b_hid l0, [2]=b_hid l1

    // ---- stage biases (one barrier for the whole kernel) ----
    if (t < H)           s_bias[0][t]       = b_in[f * H + t];
    else if (t < 2 * H)  s_bias[1][t - H]   = b_hid[(0 * F + f) * H + (t - H)];
    else if (t < 3 * H)  s_bias[2][t - 2*H] = b_hid[(1 * F + f) * H + (t - 2*H)];
    __syncthreads();

    // ---- hoist weights into registers (amortized over 8 tiles) ----
    bf16x8 Aw[2][4][2];          // [layer][m16][kk] : A[m=16*m16+l15][k=32*kk+quad*8+j]
    #pragma unroll
    for (int l = 0; l < 2; ++l)
        #pragma unroll
        for (int m = 0; m < 4; ++m) {
            if (WBF16) {
                const bf16* p = wc + ((size_t)(l * F + f) * H + m * 16 + l15) * H + quad * 8;
                Aw[l][m][0] = *(const bf16x8*)p;
                Aw[l][m][1] = *(const bf16x8*)(p + 32);
            } else {
                const float* p = w_hid + ((size_t)(l * F + f) * H + m * 16 + l15) * H + quad * 8;
                #pragma unroll
                for (int kk = 0; kk < 2; ++kk) {
                    float4 aa = *(const float4*)(p + kk * 32);
                    float4 bb = *(const float4*)(p + kk * 32 + 4);
                    bf16x8 v;
                    v[0] = (bf16)aa.x; v[1] = (bf16)aa.y; v[2] = (bf16)aa.z; v[3] = (bf16)aa.w;
                    v[4] = (bf16)bb.x; v[5] = (bf16)bb.y; v[6] = (bf16)bb.z; v[7] = (bf16)bb.w;
                    Aw[l][m][kk] = v;
                }
            }
        }

    bf16x8 A1[4];                // layer-1 A frags: quad 0 holds (w_hi, w_lo, w_hi, 0...)
    #pragma unroll
    for (int m = 0; m < 4; ++m) {
        float w  = w_in[f * H + m * 16 + l15];
        bf16 hi  = (bf16)w;
        bf16 lo  = (bf16)(w - (float)hi);
        bf16x8 v = {};
        if (quad == 0) { v[0] = hi; v[1] = lo; v[2] = hi; }
        A1[m] = v;
    }

    f32x4 wo4[4];                // w_out[16*m16+quad*4+r]
    #pragma unroll
    for (int m = 0; m < 4; ++m)
        wo4[m] = *(const f32x4*)(w_out + f * H + m * 16 + quad * 4);
    const float bo = b_out[f];

    // ---- main loop over 8 row tiles ----
    float xc0 = x[(size_t)(row0 + wrow + l15) * F + f];
    float xc1 = x[(size_t)(row0 + wrow + 16 + l15) * F + f];

    for (int it = 0; it < ITERS; ++it) {
        const int rbase = row0 + it * TILE_ROWS + wrow;

        // B1 frags: quad 0 holds (x_hi, x_hi, x_lo, 0...)
        bf16x8 B1[2];
        {
            bf16 h0 = (bf16)xc0, h1 = (bf16)xc1;
            bf16 l0 = (bf16)(xc0 - (float)h0), l1 = (bf16)(xc1 - (float)h1);
            bf16x8 v0 = {}, v1 = {};
            if (quad == 0) { v0[0] = h0; v0[1] = h0; v0[2] = l0;
                             v1[0] = h1; v1[1] = h1; v1[2] = l1; }
            B1[0] = v0; B1[1] = v1;
        }
        // prefetch next tile's x (wave-uniform branch)
        float xn0 = 0.0f, xn1 = 0.0f;
        if (it + 1 < ITERS) {
            xn0 = x[(size_t)(rbase + TILE_ROWS + l15) * F + f];
            xn1 = x[(size_t)(rbase + TILE_ROWS + 16 + l15) * F + f];
        }

        f32x4 acc[4][2];

        // ---- layer 1: one MFMA per (m,n); bias rides in as C operand ----
        #pragma unroll
        for (int m = 0; m < 4; ++m) {
            f32x4 c0 = *(const f32x4*)&s_bias[0][m * 16 + quad * 4];
            #pragma unroll
            for (int n = 0; n < 2; ++n)
                acc[m][n] = __builtin_amdgcn_mfma_f32_16x16x32_bf16(A1[m], B1[n], c0, 0, 0, 0);
        }
        #pragma unroll
        for (int m = 0; m < 4; ++m)
            #pragma unroll
            for (int n = 0; n < 2; ++n) {
                bf16x4 o;
                #pragma unroll
                for (int rr = 0; rr < 4; ++rr) o[rr] = (bf16)celu1(acc[m][n][rr]);
                *(bf16x4*)&hbuf[wrow + n * 16 + l15][m * 16 + quad * 4] = o;
            }

        // ---- hidden layer 1 (hbuf -> hbuf) ----
        {
            bf16x8 Bh[2][2];
            #pragma unroll
            for (int n = 0; n < 2; ++n)
                #pragma unroll
                for (int kk = 0; kk < 2; ++kk)
                    Bh[n][kk] = *(const bf16x8*)&hbuf[wrow + n * 16 + l15][kk * 32 + quad * 8];
            #pragma unroll
            for (int m = 0; m < 4; ++m) {
                f32x4 c0 = *(const f32x4*)&s_bias[1][m * 16 + quad * 4];
                #pragma unroll
                for (int n = 0; n < 2; ++n) {
                    f32x4 a = __builtin_amdgcn_mfma_f32_16x16x32_bf16(Aw[0][m][0], Bh[n][0], c0, 0, 0, 0);
                    acc[m][n] = __builtin_amdgcn_mfma_f32_16x16x32_bf16(Aw[0][m][1], Bh[n][1], a, 0, 0, 0);
                }
            }
            #pragma unroll
            for (int m = 0; m < 4; ++m)
                #pragma unroll
                for (int n = 0; n < 2; ++n) {
                    bf16x4 o;
                    #pragma unroll
                    for (int rr = 0; rr < 4; ++rr) o[rr] = (bf16)celu1(acc[m][n][rr]);
                    *(bf16x4*)&hbuf[wrow + n * 16 + l15][m * 16 + quad * 4] = o;
                }
        }

        // ---- hidden layer 2 + output dot (no LDS round trip) ----
        {
            bf16x8 Bh[2][2];
            #pragma unroll
            for (int n = 0; n < 2; ++n)
                #pragma unroll
                for (int kk = 0; kk < 2; ++kk)
                    Bh[n][kk] = *(const bf16x8*)&hbuf[wrow + n * 16 + l15][kk * 32 + quad * 8];
            #pragma unroll
            for (int m = 0; m < 4; ++m) {
                f32x4 c0 = *(const f32x4*)&s_bias[2][m * 16 + quad * 4];
                #pragma unroll
                for (int n = 0; n < 2; ++n) {
                    f32x4 a = __builtin_amdgcn_mfma_f32_16x16x32_bf16(Aw[1][m][0], Bh[n][0], c0, 0, 0, 0);
                    acc[m][n] = __builtin_amdgcn_mfma_f32_16x16x32_bf16(Aw[1][m][1], Bh[n][1], a, 0, 0, 0);
                }
            }
            #pragma unroll
            for (int n = 0; n < 2; ++n) {
                float sum = 0.0f;
                #pragma unroll
                for (int m = 0; m < 4; ++m)
                    #pragma unroll
                    for (int rr = 0; rr < 4; ++rr)
                        sum = fmaf(celu1(acc[m][n][rr]), wo4[m][rr], sum);
                sum += __shfl_xor(sum, 16, 64);   // reduce over quads (out-dim lives on quad*4+r, 16*m)
                sum += __shfl_xor(sum, 32, 64);
                if (quad == 0)
                    out[(size_t)(rbase + n * 16 + l15) * F + f] = sum + bo;
            }
        }

        xc0 = xn0; xc1 = xn1;
    }
}

extern "C" void kernel_launch(void* const* d_in, const int* in_sizes, int n_in,
                              void* d_out, int out_size, void* d_ws, size_t ws_size,
                              hipStream_t stream) {
    const float* x     = (const float*)d_in[0];
    const float* w_in  = (const float*)d_in[1];
    const float* b_in  = (const float*)d_in[2];
    const float* w_hid = (const float*)d_in[3];
    const float* b_hid = (const float*)d_in[4];
    const float* w_out = (const float*)d_in[5];
    const float* b_out = (const float*)d_in[6];
    float* out = (float*)d_out;

    const int Btot = in_sizes[0] / F;                       // 32768
    dim3 grid((unsigned)((Btot / ROWS_PER_BLOCK) * F));     // 32 * 64 = 2048 blocks
    dim3 block(NT);

    const int wn = 2 * F * H * H;                           // 524288 elems
    if (ws_size >= (size_t)wn * sizeof(bf16)) {
        bf16* wcp = (bf16*)d_ws;
        conv_w<<<wn / (256 * 4), 256, 0, stream>>>(w_hid, wcp);
        mlp64<true><<<grid, block, 0, stream>>>(x, w_in, b_in, w_hid, b_hid, w_out, b_out, wcp, out);
    } else {
        mlp64<false><<<grid, block, 0, stream>>>(x, w_in, b_in, w_hid, b_hid, w_out, b_out, nullptr, out);
    }
}

// Round 5
// 349.717 us; speedup vs baseline: 1.1608x; 1.1608x over previous
//
#include <hip/hip_runtime.h>

#define F 64
#define H 64
#define NT 256
#define TILE_ROWS 128
#define ITERS 8
#define ROWS_PER_BLOCK (TILE_ROWS * ITERS)   // 1024

typedef __bf16 bf16;
typedef __attribute__((ext_vector_type(8))) __bf16 bf16x8;
typedef __attribute__((ext_vector_type(4))) __bf16 bf16x4;
typedef __attribute__((ext_vector_type(4))) float f32x4;

__device__ __forceinline__ float celu1(float v) {
    // CELU(alpha=1): x>0 ? x : exp(x)-1
    float e = __expf(v) - 1.0f;
    return v > 0.0f ? v : e;
}

// fp32 -> bf16 convert of w_hid into ws (re-run every launch: ws is re-poisoned)
__global__ __launch_bounds__(256) void conv_w(const float* __restrict__ w, bf16* __restrict__ wc) {
    int i = (blockIdx.x * 256 + threadIdx.x) * 4;
    float4 v = *(const float4*)(w + i);
    bf16x4 o; o[0] = (bf16)v.x; o[1] = (bf16)v.y; o[2] = (bf16)v.z; o[3] = (bf16)v.w;
    *(bf16x4*)(wc + i) = o;
}

// [R,64] -> [64,R], coalesced both sides via 64x64 LDS tile
__global__ __launch_bounds__(256) void transpose_fwd(const float* __restrict__ src,
                                                     float* __restrict__ dst, int R) {
    __shared__ float tile[64][65];
    const int t = threadIdx.x;
    const int r0 = blockIdx.x * 64;
    {
        const int c4 = t & 15, rr = t >> 4;
        #pragma unroll
        for (int i = 0; i < 4; ++i) {
            float4 v = *(const float4*)(src + (size_t)(r0 + rr + i * 16) * 64 + c4 * 4);
            tile[rr + i * 16][c4 * 4 + 0] = v.x;
            tile[rr + i * 16][c4 * 4 + 1] = v.y;
            tile[rr + i * 16][c4 * 4 + 2] = v.z;
            tile[rr + i * 16][c4 * 4 + 3] = v.w;
        }
    }
    __syncthreads();
    {
        const int b4 = t & 15, f0 = t >> 4;
        #pragma unroll
        for (int i = 0; i < 4; ++i) {
            int ff = f0 + i * 16;
            float4 v;
            v.x = tile[b4 * 4 + 0][ff];
            v.y = tile[b4 * 4 + 1][ff];
            v.z = tile[b4 * 4 + 2][ff];
            v.w = tile[b4 * 4 + 3][ff];
            *(float4*)(dst + (size_t)ff * R + r0 + b4 * 4) = v;
        }
    }
}

// [64,R] -> [R,64]
__global__ __launch_bounds__(256) void transpose_bwd(const float* __restrict__ src,
                                                     float* __restrict__ dst, int R) {
    __shared__ float tile[64][65];
    const int t = threadIdx.x;
    const int r0 = blockIdx.x * 64;
    {
        const int b4 = t & 15, f0 = t >> 4;
        #pragma unroll
        for (int i = 0; i < 4; ++i) {
            int ff = f0 + i * 16;
            float4 v = *(const float4*)(src + (size_t)ff * R + r0 + b4 * 4);
            tile[b4 * 4 + 0][ff] = v.x;
            tile[b4 * 4 + 1][ff] = v.y;
            tile[b4 * 4 + 2][ff] = v.z;
            tile[b4 * 4 + 3][ff] = v.w;
        }
    }
    __syncthreads();
    {
        const int c4 = t & 15, rr = t >> 4;
        #pragma unroll
        for (int i = 0; i < 4; ++i) {
            float4 v;
            v.x = tile[rr + i * 16][c4 * 4 + 0];
            v.y = tile[rr + i * 16][c4 * 4 + 1];
            v.z = tile[rr + i * 16][c4 * 4 + 2];
            v.w = tile[rr + i * 16][c4 * 4 + 3];
            *(float4*)(dst + (size_t)(r0 + rr + i * 16) * 64 + c4 * 4) = v;
        }
    }
}

// XOR-swizzled LDS address: 16B chunk index ^= (row&7). Reads (b128) land 2-way
// (free, m136); epilogue b64 writes land at the 4-accesses/bank minimum.
__device__ __forceinline__ bf16* hptr(bf16* base, int row, int byteoff) {
    return (bf16*)((char*)base + row * 128 + (byteoff ^ ((row & 7) << 4)));
}

// Block = one feature f x 1024 rows. 4 waves, each owns 32 rows per 128-row tile.
// All three layers MFMA on C^T[out][batch]; weights register/AGPR-resident.
// PLANA: x from xT[F,B] (contiguous), out to outT[F,B] (contiguous).
template<bool PLANA>
__global__ __launch_bounds__(NT, 4) void mlp64(
    const float* __restrict__ x,      // [B,F] (fallback only)
    const float* __restrict__ xT,     // [F,B] (plan A)
    int Btot,
    const float* __restrict__ w_in,
    const float* __restrict__ b_in,
    const float* __restrict__ w_hid,
    const float* __restrict__ b_hid,
    const float* __restrict__ w_out,
    const float* __restrict__ b_out,
    const bf16*  __restrict__ wc,
    float* __restrict__ out,          // [B,F] (fallback only)
    float* __restrict__ outT)         // [F,B] (plan A)
{
    const int f    = blockIdx.x & (F - 1);
    const int blk  = blockIdx.x >> 6;
    const int row0 = blk * ROWS_PER_BLOCK;
    const int t    = threadIdx.x;
    const int lane = t & 63;
    const int wave = t >> 6;
    const int l15  = lane & 15;
    const int quad = lane >> 4;
    const int wrow = wave * 32;

    __shared__ __align__(16) bf16 hbuf[TILE_ROWS * 64];   // swizzled, wave-private slices
    __shared__ float s_bias[3][H];

    if (t < H)           s_bias[0][t]         = b_in[f * H + t];
    else if (t < 2 * H)  s_bias[1][t - H]     = b_hid[(0 * F + f) * H + (t - H)];
    else if (t < 3 * H)  s_bias[2][t - 2 * H] = b_hid[(1 * F + f) * H + (t - 2 * H)];
    __syncthreads();

    // ---- hoist weights (amortized over 8 tiles) ----
    bf16x8 Aw[2][4][2];          // [layer][m16][kk] : A[m=16*m16+l15][k=32*kk+quad*8+j]
    #pragma unroll
    for (int l = 0; l < 2; ++l)
        #pragma unroll
        for (int m = 0; m < 4; ++m) {
            if (PLANA) {
                const bf16* p = wc + ((size_t)(l * F + f) * H + m * 16 + l15) * H + quad * 8;
                Aw[l][m][0] = *(const bf16x8*)p;
                Aw[l][m][1] = *(const bf16x8*)(p + 32);
            } else {
                const float* p = w_hid + ((size_t)(l * F + f) * H + m * 16 + l15) * H + quad * 8;
                #pragma unroll
                for (int kk = 0; kk < 2; ++kk) {
                    float4 aa = *(const float4*)(p + kk * 32);
                    float4 bb = *(const float4*)(p + kk * 32 + 4);
                    bf16x8 v;
                    v[0] = (bf16)aa.x; v[1] = (bf16)aa.y; v[2] = (bf16)aa.z; v[3] = (bf16)aa.w;
                    v[4] = (bf16)bb.x; v[5] = (bf16)bb.y; v[6] = (bf16)bb.z; v[7] = (bf16)bb.w;
                    Aw[l][m][kk] = v;
                }
            }
        }

    bf16x8 A1[4];                // layer-1 A frags: quad 0 holds (w_hi, w_lo, w_hi, 0...)
    #pragma unroll
    for (int m = 0; m < 4; ++m) {
        float w  = w_in[f * H + m * 16 + l15];
        bf16 hi  = (bf16)w;
        bf16 lo  = (bf16)(w - (float)hi);
        bf16x8 v = {};
        if (quad == 0) { v[0] = hi; v[1] = lo; v[2] = hi; }
        A1[m] = v;
    }

    f32x4 wo4[4];
    #pragma unroll
    for (int m = 0; m < 4; ++m)
        wo4[m] = *(const f32x4*)(w_out + f * H + m * 16 + quad * 4);
    const float bo = b_out[f];

    const float* xcol = PLANA ? (xT + (size_t)f * Btot) : nullptr;
    float*       ocol = PLANA ? (outT + (size_t)f * Btot) : nullptr;

    float xc0, xc1;
    if (PLANA) {
        xc0 = xcol[row0 + wrow + l15];
        xc1 = xcol[row0 + wrow + 16 + l15];
    } else {
        xc0 = x[(size_t)(row0 + wrow + l15) * F + f];
        xc1 = x[(size_t)(row0 + wrow + 16 + l15) * F + f];
    }

    for (int it = 0; it < ITERS; ++it) {
        const int rbase = row0 + it * TILE_ROWS + wrow;

        // B1 frags: quad 0 holds (x_hi, x_hi, x_lo, 0...)
        bf16x8 B1[2];
        {
            bf16 h0 = (bf16)xc0, h1 = (bf16)xc1;
            bf16 l0 = (bf16)(xc0 - (float)h0), l1 = (bf16)(xc1 - (float)h1);
            bf16x8 v0 = {}, v1 = {};
            if (quad == 0) { v0[0] = h0; v0[1] = h0; v0[2] = l0;
                             v1[0] = h1; v1[1] = h1; v1[2] = l1; }
            B1[0] = v0; B1[1] = v1;
        }
        float xn0 = 0.0f, xn1 = 0.0f;
        if (it + 1 < ITERS) {
            if (PLANA) {
                xn0 = xcol[rbase + TILE_ROWS + l15];
                xn1 = xcol[rbase + TILE_ROWS + 16 + l15];
            } else {
                xn0 = x[(size_t)(rbase + TILE_ROWS + l15) * F + f];
                xn1 = x[(size_t)(rbase + TILE_ROWS + 16 + l15) * F + f];
            }
        }

        f32x4 acc[4][2];

        // ---- layer 1 ----
        #pragma unroll
        for (int m = 0; m < 4; ++m) {
            f32x4 c0 = *(const f32x4*)&s_bias[0][m * 16 + quad * 4];
            #pragma unroll
            for (int n = 0; n < 2; ++n)
                acc[m][n] = __builtin_amdgcn_mfma_f32_16x16x32_bf16(A1[m], B1[n], c0, 0, 0, 0);
        }
        #pragma unroll
        for (int m = 0; m < 4; ++m)
            #pragma unroll
            for (int n = 0; n < 2; ++n) {
                bf16x4 o;
                #pragma unroll
                for (int rr = 0; rr < 4; ++rr) o[rr] = (bf16)celu1(acc[m][n][rr]);
                *(bf16x4*)hptr(hbuf, wrow + n * 16 + l15, m * 32 + quad * 8) = o;
            }

        // ---- hidden layer 1 ----
        {
            bf16x8 Bh[2][2];
            #pragma unroll
            for (int n = 0; n < 2; ++n)
                #pragma unroll
                for (int kk = 0; kk < 2; ++kk)
                    Bh[n][kk] = *(const bf16x8*)hptr(hbuf, wrow + n * 16 + l15, kk * 64 + quad * 16);
            #pragma unroll
            for (int m = 0; m < 4; ++m) {
                f32x4 c0 = *(const f32x4*)&s_bias[1][m * 16 + quad * 4];
                #pragma unroll
                for (int n = 0; n < 2; ++n) {
                    f32x4 a = __builtin_amdgcn_mfma_f32_16x16x32_bf16(Aw[0][m][0], Bh[n][0], c0, 0, 0, 0);
                    acc[m][n] = __builtin_amdgcn_mfma_f32_16x16x32_bf16(Aw[0][m][1], Bh[n][1], a, 0, 0, 0);
                }
            }
            #pragma unroll
            for (int m = 0; m < 4; ++m)
                #pragma unroll
                for (int n = 0; n < 2; ++n) {
                    bf16x4 o;
                    #pragma unroll
                    for (int rr = 0; rr < 4; ++rr) o[rr] = (bf16)celu1(acc[m][n][rr]);
                    *(bf16x4*)hptr(hbuf, wrow + n * 16 + l15, m * 32 + quad * 8) = o;
                }
        }

        // ---- hidden layer 2 + output dot (register-only epilogue) ----
        {
            bf16x8 Bh[2][2];
            #pragma unroll
            for (int n = 0; n < 2; ++n)
                #pragma unroll
                for (int kk = 0; kk < 2; ++kk)
                    Bh[n][kk] = *(const bf16x8*)hptr(hbuf, wrow + n * 16 + l15, kk * 64 + quad * 16);
            #pragma unroll
            for (int m = 0; m < 4; ++m) {
                f32x4 c0 = *(const f32x4*)&s_bias[2][m * 16 + quad * 4];
                #pragma unroll
                for (int n = 0; n < 2; ++n) {
                    f32x4 a = __builtin_amdgcn_mfma_f32_16x16x32_bf16(Aw[1][m][0], Bh[n][0], c0, 0, 0, 0);
                    acc[m][n] = __builtin_amdgcn_mfma_f32_16x16x32_bf16(Aw[1][m][1], Bh[n][1], a, 0, 0, 0);
                }
            }
            #pragma unroll
            for (int n = 0; n < 2; ++n) {
                float sum = 0.0f;
                #pragma unroll
                for (int m = 0; m < 4; ++m)
                    #pragma unroll
                    for (int rr = 0; rr < 4; ++rr)
                        sum = fmaf(celu1(acc[m][n][rr]), wo4[m][rr], sum);
                sum += __shfl_xor(sum, 16, 64);
                sum += __shfl_xor(sum, 32, 64);
                if (quad == 0) {
                    if (PLANA) ocol[rbase + n * 16 + l15] = sum + bo;   // 64B contiguous
                    else out[(size_t)(rbase + n * 16 + l15) * F + f] = sum + bo;
                }
            }
        }

        xc0 = xn0; xc1 = xn1;
    }
}

extern "C" void kernel_launch(void* const* d_in, const int* in_sizes, int n_in,
                              void* d_out, int out_size, void* d_ws, size_t ws_size,
                              hipStream_t stream) {
    const float* x     = (const float*)d_in[0];
    const float* w_in  = (const float*)d_in[1];
    const float* b_in  = (const float*)d_in[2];
    const float* w_hid = (const float*)d_in[3];
    const float* b_hid = (const float*)d_in[4];
    const float* w_out = (const float*)d_in[5];
    const float* b_out = (const float*)d_in[6];
    float* out = (float*)d_out;

    const int Btot = in_sizes[0] / F;                       // 32768
    dim3 grid((unsigned)((Btot / ROWS_PER_BLOCK) * F));     // 2048 blocks
    dim3 block(NT);

    const int wn = 2 * F * H * H;                           // 524288 elems
    const size_t wc_bytes = (size_t)wn * sizeof(bf16);      // 1 MiB
    const size_t xT_bytes = (size_t)Btot * F * sizeof(float); // 8 MiB
    const size_t need = wc_bytes + 2 * xT_bytes;

    if (ws_size >= need) {
        bf16*  wcp  = (bf16*)d_ws;
        float* xT   = (float*)((char*)d_ws + wc_bytes);
        float* outT = (float*)((char*)d_ws + wc_bytes + xT_bytes);
        conv_w<<<wn / (256 * 4), 256, 0, stream>>>(w_hid, wcp);
        transpose_fwd<<<Btot / 64, 256, 0, stream>>>(x, xT, Btot);
        mlp64<true><<<grid, block, 0, stream>>>(x, xT, Btot, w_in, b_in, w_hid, b_hid,
                                                w_out, b_out, wcp, out, outT);
        transpose_bwd<<<Btot / 64, 256, 0, stream>>>(outT, out, Btot);
    } else {
        mlp64<false><<<grid, block, 0, stream>>>(x, nullptr, Btot, w_in, b_in, w_hid, b_hid,
                                                 w_out, b_out, nullptr, out, nullptr);
    }
}

// Round 6
// 189.456 us; speedup vs baseline: 2.1427x; 1.8459x over previous
//
#include <hip/hip_runtime.h>

#define F 64
#define H 64
#define NT 256
#define TILE_ROWS 128
#define ITERS 8
#define ROWS_PER_BLOCK (TILE_ROWS * ITERS)   // 1024

typedef __bf16 bf16;
typedef __attribute__((ext_vector_type(8))) __bf16 bf16x8;
typedef __attribute__((ext_vector_type(4))) __bf16 bf16x4;
typedef __attribute__((ext_vector_type(4))) float f32x4;

__device__ __forceinline__ float celu1(float v) {
    // CELU(alpha=1): x>0 ? x : exp(x)-1
    float e = __expf(v) - 1.0f;
    return v > 0.0f ? v : e;
}

// fp32 -> bf16 convert of w_hid into ws (re-run every launch: ws is re-poisoned)
__global__ __launch_bounds__(256) void conv_w(const float* __restrict__ w, bf16* __restrict__ wc) {
    int i = (blockIdx.x * 256 + threadIdx.x) * 4;
    float4 v = *(const float4*)(w + i);
    bf16x4 o; o[0] = (bf16)v.x; o[1] = (bf16)v.y; o[2] = (bf16)v.z; o[3] = (bf16)v.w;
    *(bf16x4*)(wc + i) = o;
}

// [R,64] -> [64,R], coalesced both sides via 64x64 LDS tile
__global__ __launch_bounds__(256) void transpose_fwd(const float* __restrict__ src,
                                                     float* __restrict__ dst, int R) {
    __shared__ float tile[64][65];
    const int t = threadIdx.x;
    const int r0 = blockIdx.x * 64;
    {
        const int c4 = t & 15, rr = t >> 4;
        #pragma unroll
        for (int i = 0; i < 4; ++i) {
            float4 v = *(const float4*)(src + (size_t)(r0 + rr + i * 16) * 64 + c4 * 4);
            tile[rr + i * 16][c4 * 4 + 0] = v.x;
            tile[rr + i * 16][c4 * 4 + 1] = v.y;
            tile[rr + i * 16][c4 * 4 + 2] = v.z;
            tile[rr + i * 16][c4 * 4 + 3] = v.w;
        }
    }
    __syncthreads();
    {
        const int b4 = t & 15, f0 = t >> 4;
        #pragma unroll
        for (int i = 0; i < 4; ++i) {
            int ff = f0 + i * 16;
            float4 v;
            v.x = tile[b4 * 4 + 0][ff];
            v.y = tile[b4 * 4 + 1][ff];
            v.z = tile[b4 * 4 + 2][ff];
            v.w = tile[b4 * 4 + 3][ff];
            *(float4*)(dst + (size_t)ff * R + r0 + b4 * 4) = v;
        }
    }
}

// [64,R] -> [R,64]
__global__ __launch_bounds__(256) void transpose_bwd(const float* __restrict__ src,
                                                     float* __restrict__ dst, int R) {
    __shared__ float tile[64][65];
    const int t = threadIdx.x;
    const int r0 = blockIdx.x * 64;
    {
        const int b4 = t & 15, f0 = t >> 4;
        #pragma unroll
        for (int i = 0; i < 4; ++i) {
            int ff = f0 + i * 16;
            float4 v = *(const float4*)(src + (size_t)ff * R + r0 + b4 * 4);
            tile[b4 * 4 + 0][ff] = v.x;
            tile[b4 * 4 + 1][ff] = v.y;
            tile[b4 * 4 + 2][ff] = v.z;
            tile[b4 * 4 + 3][ff] = v.w;
        }
    }
    __syncthreads();
    {
        const int c4 = t & 15, rr = t >> 4;
        #pragma unroll
        for (int i = 0; i < 4; ++i) {
            float4 v;
            v.x = tile[rr + i * 16][c4 * 4 + 0];
            v.y = tile[rr + i * 16][c4 * 4 + 1];
            v.z = tile[rr + i * 16][c4 * 4 + 2];
            v.w = tile[rr + i * 16][c4 * 4 + 3];
            *(float4*)(dst + (size_t)(r0 + rr + i * 16) * 64 + c4 * 4) = v;
        }
    }
}

// XOR-swizzled LDS address: 16B chunk index ^= (row&7).
__device__ __forceinline__ bf16* hptr(bf16* base, int row, int byteoff) {
    return (bf16*)((char*)base + row * 128 + (byteoff ^ ((row & 7) << 4)));
}

// Block = one feature f x 1024 rows. 4 waves, each owns 32 rows per 128-row tile.
// All three layers MFMA on C^T[out][batch]; weights register/AGPR-resident.
// __launch_bounds__(256,2): 256-reg unified budget -- the ~185 live regs (Aw 64 +
// A1/wo4/acc/Bh/B1 + temps) MUST NOT SPILL (R3-R5: spills to scratch showed up as
// 0.5-1.0 GB of FETCH_SIZE and 3x slowdown).
template<bool PLANA>
__global__ __launch_bounds__(NT, 2) void mlp64(
    const float* __restrict__ x,      // [B,F] (fallback only)
    const float* __restrict__ xT,     // [F,B] (plan A)
    int Btot,
    const float* __restrict__ w_in,
    const float* __restrict__ b_in,
    const float* __restrict__ w_hid,
    const float* __restrict__ b_hid,
    const float* __restrict__ w_out,
    const float* __restrict__ b_out,
    const bf16*  __restrict__ wc,
    float* __restrict__ out,          // [B,F] (fallback only)
    float* __restrict__ outT)         // [F,B] (plan A)
{
    const int f    = blockIdx.x & (F - 1);
    const int blk  = blockIdx.x >> 6;
    const int row0 = blk * ROWS_PER_BLOCK;
    const int t    = threadIdx.x;
    const int lane = t & 63;
    const int wave = t >> 6;
    const int l15  = lane & 15;
    const int quad = lane >> 4;
    const int wrow = wave * 32;

    __shared__ __align__(16) bf16 hbuf[TILE_ROWS * 64];   // swizzled, wave-private slices
    __shared__ float s_bias[3][H];

    if (t < H)           s_bias[0][t]         = b_in[f * H + t];
    else if (t < 2 * H)  s_bias[1][t - H]     = b_hid[(0 * F + f) * H + (t - H)];
    else if (t < 3 * H)  s_bias[2][t - 2 * H] = b_hid[(1 * F + f) * H + (t - 2 * H)];
    __syncthreads();

    // ---- hoist weights (amortized over 8 tiles) ----
    bf16x8 Aw[2][4][2];          // [layer][m16][kk] : A[m=16*m16+l15][k=32*kk+quad*8+j]
    #pragma unroll
    for (int l = 0; l < 2; ++l)
        #pragma unroll
        for (int m = 0; m < 4; ++m) {
            if (PLANA) {
                const bf16* p = wc + ((size_t)(l * F + f) * H + m * 16 + l15) * H + quad * 8;
                Aw[l][m][0] = *(const bf16x8*)p;
                Aw[l][m][1] = *(const bf16x8*)(p + 32);
            } else {
                const float* p = w_hid + ((size_t)(l * F + f) * H + m * 16 + l15) * H + quad * 8;
                #pragma unroll
                for (int kk = 0; kk < 2; ++kk) {
                    float4 aa = *(const float4*)(p + kk * 32);
                    float4 bb = *(const float4*)(p + kk * 32 + 4);
                    bf16x8 v;
                    v[0] = (bf16)aa.x; v[1] = (bf16)aa.y; v[2] = (bf16)aa.z; v[3] = (bf16)aa.w;
                    v[4] = (bf16)bb.x; v[5] = (bf16)bb.y; v[6] = (bf16)bb.z; v[7] = (bf16)bb.w;
                    Aw[l][m][kk] = v;
                }
            }
        }

    bf16x8 A1[4];                // layer-1 A frags: quad 0 holds (w_hi, w_lo, w_hi, 0...)
    #pragma unroll
    for (int m = 0; m < 4; ++m) {
        float w  = w_in[f * H + m * 16 + l15];
        bf16 hi  = (bf16)w;
        bf16 lo  = (bf16)(w - (float)hi);
        bf16x8 v = {};
        if (quad == 0) { v[0] = hi; v[1] = lo; v[2] = hi; }
        A1[m] = v;
    }

    f32x4 wo4[4];
    #pragma unroll
    for (int m = 0; m < 4; ++m)
        wo4[m] = *(const f32x4*)(w_out + f * H + m * 16 + quad * 4);
    const float bo = b_out[f];

    const float* xcol = PLANA ? (xT + (size_t)f * Btot) : nullptr;
    float*       ocol = PLANA ? (outT + (size_t)f * Btot) : nullptr;

    float xc0, xc1;
    if (PLANA) {
        xc0 = xcol[row0 + wrow + l15];
        xc1 = xcol[row0 + wrow + 16 + l15];
    } else {
        xc0 = x[(size_t)(row0 + wrow + l15) * F + f];
        xc1 = x[(size_t)(row0 + wrow + 16 + l15) * F + f];
    }

    #pragma unroll 1
    for (int it = 0; it < ITERS; ++it) {
        const int rbase = row0 + it * TILE_ROWS + wrow;

        // B1 frags: quad 0 holds (x_hi, x_hi, x_lo, 0...)
        bf16x8 B1[2];
        {
            bf16 h0 = (bf16)xc0, h1 = (bf16)xc1;
            bf16 l0 = (bf16)(xc0 - (float)h0), l1 = (bf16)(xc1 - (float)h1);
            bf16x8 v0 = {}, v1 = {};
            if (quad == 0) { v0[0] = h0; v0[1] = h0; v0[2] = l0;
                             v1[0] = h1; v1[1] = h1; v1[2] = l1; }
            B1[0] = v0; B1[1] = v1;
        }
        float xn0 = 0.0f, xn1 = 0.0f;
        if (it + 1 < ITERS) {
            if (PLANA) {
                xn0 = xcol[rbase + TILE_ROWS + l15];
                xn1 = xcol[rbase + TILE_ROWS + 16 + l15];
            } else {
                xn0 = x[(size_t)(rbase + TILE_ROWS + l15) * F + f];
                xn1 = x[(size_t)(rbase + TILE_ROWS + 16 + l15) * F + f];
            }
        }

        f32x4 acc[4][2];

        // ---- layer 1 ----
        #pragma unroll
        for (int m = 0; m < 4; ++m) {
            f32x4 c0 = *(const f32x4*)&s_bias[0][m * 16 + quad * 4];
            #pragma unroll
            for (int n = 0; n < 2; ++n)
                acc[m][n] = __builtin_amdgcn_mfma_f32_16x16x32_bf16(A1[m], B1[n], c0, 0, 0, 0);
        }
        #pragma unroll
        for (int m = 0; m < 4; ++m)
            #pragma unroll
            for (int n = 0; n < 2; ++n) {
                bf16x4 o;
                #pragma unroll
                for (int rr = 0; rr < 4; ++rr) o[rr] = (bf16)celu1(acc[m][n][rr]);
                *(bf16x4*)hptr(hbuf, wrow + n * 16 + l15, m * 32 + quad * 8) = o;
            }

        // ---- hidden layer 1 ----
        {
            bf16x8 Bh[2][2];
            #pragma unroll
            for (int n = 0; n < 2; ++n)
                #pragma unroll
                for (int kk = 0; kk < 2; ++kk)
                    Bh[n][kk] = *(const bf16x8*)hptr(hbuf, wrow + n * 16 + l15, kk * 64 + quad * 16);
            #pragma unroll
            for (int m = 0; m < 4; ++m) {
                f32x4 c0 = *(const f32x4*)&s_bias[1][m * 16 + quad * 4];
                #pragma unroll
                for (int n = 0; n < 2; ++n) {
                    f32x4 a = __builtin_amdgcn_mfma_f32_16x16x32_bf16(Aw[0][m][0], Bh[n][0], c0, 0, 0, 0);
                    acc[m][n] = __builtin_amdgcn_mfma_f32_16x16x32_bf16(Aw[0][m][1], Bh[n][1], a, 0, 0, 0);
                }
            }
            #pragma unroll
            for (int m = 0; m < 4; ++m)
                #pragma unroll
                for (int n = 0; n < 2; ++n) {
                    bf16x4 o;
                    #pragma unroll
                    for (int rr = 0; rr < 4; ++rr) o[rr] = (bf16)celu1(acc[m][n][rr]);
                    *(bf16x4*)hptr(hbuf, wrow + n * 16 + l15, m * 32 + quad * 8) = o;
                }
        }

        // ---- hidden layer 2 + output dot (register-only epilogue) ----
        {
            bf16x8 Bh[2][2];
            #pragma unroll
            for (int n = 0; n < 2; ++n)
                #pragma unroll
                for (int kk = 0; kk < 2; ++kk)
                    Bh[n][kk] = *(const bf16x8*)hptr(hbuf, wrow + n * 16 + l15, kk * 64 + quad * 16);
            #pragma unroll
            for (int m = 0; m < 4; ++m) {
                f32x4 c0 = *(const f32x4*)&s_bias[2][m * 16 + quad * 4];
                #pragma unroll
                for (int n = 0; n < 2; ++n) {
                    f32x4 a = __builtin_amdgcn_mfma_f32_16x16x32_bf16(Aw[1][m][0], Bh[n][0], c0, 0, 0, 0);
                    acc[m][n] = __builtin_amdgcn_mfma_f32_16x16x32_bf16(Aw[1][m][1], Bh[n][1], a, 0, 0, 0);
                }
            }
            #pragma unroll
            for (int n = 0; n < 2; ++n) {
                float sum = 0.0f;
                #pragma unroll
                for (int m = 0; m < 4; ++m)
                    #pragma unroll
                    for (int rr = 0; rr < 4; ++rr)
                        sum = fmaf(celu1(acc[m][n][rr]), wo4[m][rr], sum);
                sum += __shfl_xor(sum, 16, 64);
                sum += __shfl_xor(sum, 32, 64);
                if (quad == 0) {
                    if (PLANA) ocol[rbase + n * 16 + l15] = sum + bo;   // 64B contiguous
                    else out[(size_t)(rbase + n * 16 + l15) * F + f] = sum + bo;
                }
            }
        }

        xc0 = xn0; xc1 = xn1;
    }
}

extern "C" void kernel_launch(void* const* d_in, const int* in_sizes, int n_in,
                              void* d_out, int out_size, void* d_ws, size_t ws_size,
                              hipStream_t stream) {
    const float* x     = (const float*)d_in[0];
    const float* w_in  = (const float*)d_in[1];
    const float* b_in  = (const float*)d_in[2];
    const float* w_hid = (const float*)d_in[3];
    const float* b_hid = (const float*)d_in[4];
    const float* w_out = (const float*)d_in[5];
    const float* b_out = (const float*)d_in[6];
    float* out = (float*)d_out;

    const int Btot = in_sizes[0] / F;                       // 32768
    dim3 grid((unsigned)((Btot / ROWS_PER_BLOCK) * F));     // 2048 blocks
    dim3 block(NT);

    const int wn = 2 * F * H * H;                           // 524288 elems
    const size_t wc_bytes = (size_t)wn * sizeof(bf16);      // 1 MiB
    const size_t xT_bytes = (size_t)Btot * F * sizeof(float); // 8 MiB
    const size_t need = wc_bytes + 2 * xT_bytes;

    if (ws_size >= need) {
        bf16*  wcp  = (bf16*)d_ws;
        float* xT   = (float*)((char*)d_ws + wc_bytes);
        float* outT = (float*)((char*)d_ws + wc_bytes + xT_bytes);
        conv_w<<<wn / (256 * 4), 256, 0, stream>>>(w_hid, wcp);
        transpose_fwd<<<Btot / 64, 256, 0, stream>>>(x, xT, Btot);
        mlp64<true><<<grid, block, 0, stream>>>(x, xT, Btot, w_in, b_in, w_hid, b_hid,
                                                w_out, b_out, wcp, out, outT);
        transpose_bwd<<<Btot / 64, 256, 0, stream>>>(outT, out, Btot);
    } else {
        mlp64<false><<<grid, block, 0, stream>>>(x, nullptr, Btot, w_in, b_in, w_hid, b_hid,
                                                 w_out, b_out, nullptr, out, nullptr);
    }
}

// Round 7
// 181.972 us; speedup vs baseline: 2.2308x; 1.0411x over previous
//
#include <hip/hip_runtime.h>

#define F 64
#define H 64
#define NT 256
#define TILE_ROWS 128
#define ITERS 8
#define ROWS_PER_BLOCK (TILE_ROWS * ITERS)   // 1024
#define WPAD 72   // LDS row stride in bf16 elems (144 B = 36 words): conflict-free for the
                  // MFMA read (b128 @ kk*64+q*16) and write (b64 @ m*32+q*8) patterns below

typedef __bf16 bf16;
typedef __attribute__((ext_vector_type(8))) __bf16 bf16x8;
typedef __attribute__((ext_vector_type(4))) __bf16 bf16x4;
typedef __attribute__((ext_vector_type(4))) float f32x4;

__device__ __forceinline__ float celu1(float v) {
    // CELU(alpha=1): x>0 ? x : exp(x)-1
    float e = __expf(v) - 1.0f;
    return v > 0.0f ? v : e;
}

// fused prep: blocks [0,512): w_hid fp32->bf16 into wc; blocks [512,512+R/64): x[R,64]->xT[64,R]
__global__ __launch_bounds__(256) void prep(const float* __restrict__ w, bf16* __restrict__ wc,
                                            const float* __restrict__ x, float* __restrict__ xT,
                                            int R) {
    const int t = threadIdx.x;
    __shared__ float tile[64][65];
    if (blockIdx.x < 512) {
        int i = (blockIdx.x * 256 + t) * 4;
        float4 v = *(const float4*)(w + i);
        bf16x4 o; o[0] = (bf16)v.x; o[1] = (bf16)v.y; o[2] = (bf16)v.z; o[3] = (bf16)v.w;
        *(bf16x4*)(wc + i) = o;
        return;
    }
    const int r0 = (int)(blockIdx.x - 512) * 64;
    {
        const int c4 = t & 15, rr = t >> 4;
        #pragma unroll
        for (int i = 0; i < 4; ++i) {
            float4 v = *(const float4*)(x + (size_t)(r0 + rr + i * 16) * 64 + c4 * 4);
            tile[rr + i * 16][c4 * 4 + 0] = v.x;
            tile[rr + i * 16][c4 * 4 + 1] = v.y;
            tile[rr + i * 16][c4 * 4 + 2] = v.z;
            tile[rr + i * 16][c4 * 4 + 3] = v.w;
        }
    }
    __syncthreads();
    {
        const int b4 = t & 15, f0 = t >> 4;
        #pragma unroll
        for (int i = 0; i < 4; ++i) {
            int ff = f0 + i * 16;
            float4 v;
            v.x = tile[b4 * 4 + 0][ff];
            v.y = tile[b4 * 4 + 1][ff];
            v.z = tile[b4 * 4 + 2][ff];
            v.w = tile[b4 * 4 + 3][ff];
            *(float4*)(xT + (size_t)ff * R + r0 + b4 * 4) = v;
        }
    }
}

// [64,R] -> [R,64]
__global__ __launch_bounds__(256) void transpose_bwd(const float* __restrict__ src,
                                                     float* __restrict__ dst, int R) {
    __shared__ float tile[64][65];
    const int t = threadIdx.x;
    const int r0 = blockIdx.x * 64;
    {
        const int b4 = t & 15, f0 = t >> 4;
        #pragma unroll
        for (int i = 0; i < 4; ++i) {
            int ff = f0 + i * 16;
            float4 v = *(const float4*)(src + (size_t)ff * R + r0 + b4 * 4);
            tile[b4 * 4 + 0][ff] = v.x;
            tile[b4 * 4 + 1][ff] = v.y;
            tile[b4 * 4 + 2][ff] = v.z;
            tile[b4 * 4 + 3][ff] = v.w;
        }
    }
    __syncthreads();
    {
        const int c4 = t & 15, rr = t >> 4;
        #pragma unroll
        for (int i = 0; i < 4; ++i) {
            float4 v;
            v.x = tile[rr + i * 16][c4 * 4 + 0];
            v.y = tile[rr + i * 16][c4 * 4 + 1];
            v.z = tile[rr + i * 16][c4 * 4 + 2];
            v.w = tile[rr + i * 16][c4 * 4 + 3];
            *(float4*)(dst + (size_t)(r0 + rr + i * 16) * 64 + c4 * 4) = v;
        }
    }
}

// Block = one feature f x 1024 rows; 4 waves x 32 wave-private rows per 128-row tile; no
// inner barriers. Hidden layer 0 weights in regs, hidden layer 1 weights in LDS (reg-pressure
// split: live set ~140 regs -> 3 waves/SIMD without spills; R3-R5 showed spills = GB-scale
// FETCH_SIZE). All layers MFMA on C^T[out][batch]; D: col=batch=l15, row=out=16m+4q+r.
template<bool PLANA>
__global__ __launch_bounds__(NT, 3) void mlp64(
    const float* __restrict__ x,      // [B,F] (fallback only)
    const float* __restrict__ xT,     // [F,B] (plan A)
    int Btot,
    const float* __restrict__ w_in,
    const float* __restrict__ b_in,
    const float* __restrict__ w_hid,
    const float* __restrict__ b_hid,
    const float* __restrict__ w_out,
    const float* __restrict__ b_out,
    const bf16*  __restrict__ wc,
    float* __restrict__ out,          // [B,F] (fallback only)
    float* __restrict__ outT)         // [F,B] (plan A)
{
    const int f    = blockIdx.x & (F - 1);
    const int blk  = blockIdx.x >> 6;
    const int row0 = blk * ROWS_PER_BLOCK;
    const int t    = threadIdx.x;
    const int lane = t & 63;
    const int wave = t >> 6;
    const int l15  = lane & 15;
    const int q    = lane >> 4;
    const int wrow = wave * 32;

    __shared__ __align__(16) bf16 hbuf[TILE_ROWS][WPAD];
    __shared__ __align__(16) bf16 wlds[H][WPAD];          // hidden layer 1 weights [out][in]
    __shared__ __align__(16) float s_bias[3][H];

    // ---- stage hidden-layer-1 weights into padded LDS rows (coalesced 16B chunks) ----
    for (int idx = t; idx < 512; idx += NT) {
        const int row = idx >> 3, ch = idx & 7;
        if (PLANA) {
            bf16x8 v = *(const bf16x8*)(wc + (((size_t)F + f) << 12) + (row << 6) + (ch << 3));
            *(bf16x8*)&wlds[row][ch * 8] = v;
        } else {
            const float* p = w_hid + (((size_t)F + f) << 12) + (row << 6) + (ch << 3);
            float4 a = *(const float4*)p, b = *(const float4*)(p + 4);
            bf16x8 v;
            v[0] = (bf16)a.x; v[1] = (bf16)a.y; v[2] = (bf16)a.z; v[3] = (bf16)a.w;
            v[4] = (bf16)b.x; v[5] = (bf16)b.y; v[6] = (bf16)b.z; v[7] = (bf16)b.w;
            *(bf16x8*)&wlds[row][ch * 8] = v;
        }
    }
    if (t < H)           s_bias[0][t]         = b_in[f * H + t];
    else if (t < 2 * H)  s_bias[1][t - H]     = b_hid[(0 * F + f) * H + (t - H)];
    else if (t < 3 * H)  s_bias[2][t - 2 * H] = b_hid[(1 * F + f) * H + (t - 2 * H)];
    __syncthreads();

    // ---- hidden-layer-0 weights in registers ----
    bf16x8 Aw0[4][2];            // A[m=16m+l15][k=32kk+q*8+j]
    #pragma unroll
    for (int m = 0; m < 4; ++m) {
        if (PLANA) {
            const bf16* p = wc + ((size_t)f << 12) + (m * 16 + l15) * 64 + q * 8;
            Aw0[m][0] = *(const bf16x8*)p;
            Aw0[m][1] = *(const bf16x8*)(p + 32);
        } else {
            const float* p = w_hid + ((size_t)f << 12) + (m * 16 + l15) * 64 + q * 8;
            #pragma unroll
            for (int kk = 0; kk < 2; ++kk) {
                float4 a = *(const float4*)(p + kk * 32), b = *(const float4*)(p + kk * 32 + 4);
                bf16x8 v;
                v[0] = (bf16)a.x; v[1] = (bf16)a.y; v[2] = (bf16)a.z; v[3] = (bf16)a.w;
                v[4] = (bf16)b.x; v[5] = (bf16)b.y; v[6] = (bf16)b.z; v[7] = (bf16)b.w;
                Aw0[m][kk] = v;
            }
        }
    }

    bf16x8 A1[4];                // layer-in A frags: quad 0 holds (w_hi, w_lo, w_hi, 0...)
    #pragma unroll
    for (int m = 0; m < 4; ++m) {
        float w  = w_in[f * H + m * 16 + l15];
        bf16 hi  = (bf16)w;
        bf16 lo  = (bf16)(w - (float)hi);
        bf16x8 v = {};
        if (q == 0) { v[0] = hi; v[1] = lo; v[2] = hi; }
        A1[m] = v;
    }

    f32x4 wo4[4];
    #pragma unroll
    for (int m = 0; m < 4; ++m)
        wo4[m] = *(const f32x4*)(w_out + f * H + m * 16 + q * 4);
    const float bo = b_out[f];

    const float* xcol = PLANA ? (xT + (size_t)f * Btot) : nullptr;
    float*       ocol = PLANA ? (outT + (size_t)f * Btot) : nullptr;

    float xc0, xc1;
    if (PLANA) {
        xc0 = xcol[row0 + wrow + l15];
        xc1 = xcol[row0 + wrow + 16 + l15];
    } else {
        xc0 = x[(size_t)(row0 + wrow + l15) * F + f];
        xc1 = x[(size_t)(row0 + wrow + 16 + l15) * F + f];
    }

    #pragma unroll 1
    for (int it = 0; it < ITERS; ++it) {
        const int rbase = row0 + it * TILE_ROWS + wrow;

        // B1 frags: quad 0 holds (x_hi, x_hi, x_lo, 0...)
        bf16x8 B1[2];
        {
            bf16 h0 = (bf16)xc0, h1 = (bf16)xc1;
            bf16 l0 = (bf16)(xc0 - (float)h0), l1 = (bf16)(xc1 - (float)h1);
            bf16x8 v0 = {}, v1 = {};
            if (q == 0) { v0[0] = h0; v0[1] = h0; v0[2] = l0;
                          v1[0] = h1; v1[1] = h1; v1[2] = l1; }
            B1[0] = v0; B1[1] = v1;
        }
        float xn0 = 0.0f, xn1 = 0.0f;
        if (it + 1 < ITERS) {
            if (PLANA) {
                xn0 = xcol[rbase + TILE_ROWS + l15];
                xn1 = xcol[rbase + TILE_ROWS + 16 + l15];
            } else {
                xn0 = x[(size_t)(rbase + TILE_ROWS + l15) * F + f];
                xn1 = x[(size_t)(rbase + TILE_ROWS + 16 + l15) * F + f];
            }
        }

        // ---- layer in->H (per-m: 2 MFMA, celu, b64 write) ----
        #pragma unroll
        for (int m = 0; m < 4; ++m) {
            f32x4 c0 = *(const f32x4*)&s_bias[0][m * 16 + q * 4];
            f32x4 a0 = __builtin_amdgcn_mfma_f32_16x16x32_bf16(A1[m], B1[0], c0, 0, 0, 0);
            f32x4 a1 = __builtin_amdgcn_mfma_f32_16x16x32_bf16(A1[m], B1[1], c0, 0, 0, 0);
            bf16x4 o0, o1;
            #pragma unroll
            for (int rr = 0; rr < 4; ++rr) { o0[rr] = (bf16)celu1(a0[rr]); o1[rr] = (bf16)celu1(a1[rr]); }
            *(bf16x4*)&hbuf[wrow + l15][m * 16 + q * 4]      = o0;
            *(bf16x4*)&hbuf[wrow + 16 + l15][m * 16 + q * 4] = o1;
        }

        // ---- hidden layer 0 (register weights) ----
        {
            bf16x8 Bh[2][2];
            #pragma unroll
            for (int n = 0; n < 2; ++n)
                #pragma unroll
                for (int kk = 0; kk < 2; ++kk)
                    Bh[n][kk] = *(const bf16x8*)&hbuf[wrow + n * 16 + l15][kk * 32 + q * 8];
            #pragma unroll
            for (int m = 0; m < 4; ++m) {
                f32x4 c0 = *(const f32x4*)&s_bias[1][m * 16 + q * 4];
                f32x4 a0 = __builtin_amdgcn_mfma_f32_16x16x32_bf16(Aw0[m][0], Bh[0][0], c0, 0, 0, 0);
                a0       = __builtin_amdgcn_mfma_f32_16x16x32_bf16(Aw0[m][1], Bh[0][1], a0, 0, 0, 0);
                f32x4 a1 = __builtin_amdgcn_mfma_f32_16x16x32_bf16(Aw0[m][0], Bh[1][0], c0, 0, 0, 0);
                a1       = __builtin_amdgcn_mfma_f32_16x16x32_bf16(Aw0[m][1], Bh[1][1], a1, 0, 0, 0);
                bf16x4 o0, o1;
                #pragma unroll
                for (int rr = 0; rr < 4; ++rr) { o0[rr] = (bf16)celu1(a0[rr]); o1[rr] = (bf16)celu1(a1[rr]); }
                *(bf16x4*)&hbuf[wrow + l15][m * 16 + q * 4]      = o0;
                *(bf16x4*)&hbuf[wrow + 16 + l15][m * 16 + q * 4] = o1;
            }
        }

        // ---- hidden layer 1 (LDS weights) + output dot in registers ----
        {
            bf16x8 Bh[2][2];
            #pragma unroll
            for (int n = 0; n < 2; ++n)
                #pragma unroll
                for (int kk = 0; kk < 2; ++kk)
                    Bh[n][kk] = *(const bf16x8*)&hbuf[wrow + n * 16 + l15][kk * 32 + q * 8];
            float s0 = 0.0f, s1 = 0.0f;
            #pragma unroll
            for (int m = 0; m < 4; ++m) {
                bf16x8 Awt0 = *(const bf16x8*)&wlds[m * 16 + l15][q * 8];
                bf16x8 Awt1 = *(const bf16x8*)&wlds[m * 16 + l15][32 + q * 8];
                f32x4 c0 = *(const f32x4*)&s_bias[2][m * 16 + q * 4];
                f32x4 a0 = __builtin_amdgcn_mfma_f32_16x16x32_bf16(Awt0, Bh[0][0], c0, 0, 0, 0);
                a0       = __builtin_amdgcn_mfma_f32_16x16x32_bf16(Awt1, Bh[0][1], a0, 0, 0, 0);
                f32x4 a1 = __builtin_amdgcn_mfma_f32_16x16x32_bf16(Awt0, Bh[1][0], c0, 0, 0, 0);
                a1       = __builtin_amdgcn_mfma_f32_16x16x32_bf16(Awt1, Bh[1][1], a1, 0, 0, 0);
                #pragma unroll
                for (int rr = 0; rr < 4; ++rr) {
                    s0 = fmaf(celu1(a0[rr]), wo4[m][rr], s0);
                    s1 = fmaf(celu1(a1[rr]), wo4[m][rr], s1);
                }
            }
            s0 += __shfl_xor(s0, 16, 64);
            s0 += __shfl_xor(s0, 32, 64);
            s1 += __shfl_xor(s1, 16, 64);
            s1 += __shfl_xor(s1, 32, 64);
            if (q == 0) {
                if (PLANA) {
                    ocol[rbase + l15]      = s0 + bo;
                    ocol[rbase + 16 + l15] = s1 + bo;
                } else {
                    out[(size_t)(rbase + l15) * F + f]      = s0 + bo;
                    out[(size_t)(rbase + 16 + l15) * F + f] = s1 + bo;
                }
            }
        }

        xc0 = xn0; xc1 = xn1;
    }
}

extern "C" void kernel_launch(void* const* d_in, const int* in_sizes, int n_in,
                              void* d_out, int out_size, void* d_ws, size_t ws_size,
                              hipStream_t stream) {
    const float* x     = (const float*)d_in[0];
    const float* w_in  = (const float*)d_in[1];
    const float* b_in  = (const float*)d_in[2];
    const float* w_hid = (const float*)d_in[3];
    const float* b_hid = (const float*)d_in[4];
    const float* w_out = (const float*)d_in[5];
    const float* b_out = (const float*)d_in[6];
    float* out = (float*)d_out;

    const int Btot = in_sizes[0] / F;                       // 32768
    dim3 grid((unsigned)((Btot / ROWS_PER_BLOCK) * F));     // 2048 blocks
    dim3 block(NT);

    const int wn = 2 * F * H * H;                           // 524288 elems
    const size_t wc_bytes = (size_t)wn * sizeof(bf16);      // 1 MiB
    const size_t xT_bytes = (size_t)Btot * F * sizeof(float); // 8 MiB
    const size_t need = wc_bytes + 2 * xT_bytes;

    if (ws_size >= need) {
        bf16*  wcp  = (bf16*)d_ws;
        float* xT   = (float*)((char*)d_ws + wc_bytes);
        float* outT = (float*)((char*)d_ws + wc_bytes + xT_bytes);
        prep<<<512 + Btot / 64, 256, 0, stream>>>(w_hid, wcp, x, xT, Btot);
        mlp64<true><<<grid, block, 0, stream>>>(x, xT, Btot, w_in, b_in, w_hid, b_hid,
                                                w_out, b_out, wcp, out, outT);
        transpose_bwd<<<Btot / 64, 256, 0, stream>>>(outT, out, Btot);
    } else {
        mlp64<false><<<grid, block, 0, stream>>>(x, nullptr, Btot, w_in, b_in, w_hid, b_hid,
                                                 w_out, b_out, nullptr, out, nullptr);
    }
}